// Round 7
// baseline (130.972 us; speedup 1.0000x reference)
//
#include <hip/hip_runtime.h>
#include <hip/hip_bf16.h>

// Problem: features_1 [1,20000,256] f32, features_2 [1,8192,256] f32, map21 [8192] int
#define PP      8192
#define DIM     256
#define DIMP    272              // 256 + 16 pad dims (norm embedding in 4 of them)
#define NKF     17               // K fragments of 16
#define GS      (32 * DIMP)      // 8704 bf16 elems per 32-row group
#define NCHUNK  16               // column chunks (grid.y); chunk = 512 cols
#define TCOLS   16               // 32-col tiles per chunk
#define ROWBLK  256              // rows per main block (4 waves x 2 row-groups)
#define NROWBLK (PP / ROWBLK)    // 32
#define TILEB   (32 * DIMP * 2)  // 17408 B per 32-col B tile
#define NBUF    2                // LDS double buffer

typedef __bf16 bf16_t;
using bf16x8 = __attribute__((ext_vector_type(8))) __bf16;
using bf16x4 = __attribute__((ext_vector_type(4))) __bf16;
using f32x4  = __attribute__((ext_vector_type(4))) float;
using f32x16 = __attribute__((ext_vector_type(16))) float;

typedef __attribute__((address_space(1))) void as1_void;
typedef __attribute__((address_space(3))) void as3_void;

#define C2    20.609929155556618          // 1/(T*ln2): -dist -> log2-domain logit
#define MEXP  (-340.0f)                   // fixed log2 shift (safe: see analysis)
#define COEF  ((float)(-(C2 * 1.4142135623730951) * 8388608.0))  // -C2*sqrt(2)*2^23
#define KBIAS ((float)((127.0 + 340.0) * 8388608.0))             // (127 - MEXP)*2^23
#define LN2   0.6931471805599453f

// ---------------------------------------------------------------------------
// Kernel 1: gather + bf16 convert into frag-major layout + norm-embedding pad
// dims + exact fp32 diagonal logit. Also zero-inits part_l / counters / out.
// One wave per row p; lane covers k = lane*4 .. +3.   (UNCHANGED)
// ---------------------------------------------------------------------------
__global__ __launch_bounds__(256) void nce_prep(
    const float* __restrict__ f1, const float* __restrict__ f2,
    const int* __restrict__ map,
    bf16_t* __restrict__ qb2, bf16_t* __restrict__ kb2,
    float* __restrict__ diag2, float* __restrict__ part_l,
    unsigned* __restrict__ cnt, float* __restrict__ out)
{
    const int tid  = threadIdx.x;
    const int wave = tid >> 6, lane = tid & 63;
    const int p    = blockIdx.x * 4 + wave;
    const int gtid = blockIdx.x * 256 + tid;

    if (gtid < PP) part_l[gtid] = 0.0f;
    if (gtid < NROWBLK) cnt[gtid] = 0u;
    if (gtid == 0) out[0] = 0.0f;

    const int idx = map[p];
    const f32x4 qv = *(const f32x4*)(f1 + (size_t)idx * DIM + lane * 4);
    const f32x4 kv = *(const f32x4*)(f2 + (size_t)p * DIM + lane * 4);

    float qs = qv[0]*qv[0] + qv[1]*qv[1] + qv[2]*qv[2] + qv[3]*qv[3];
    float ks = kv[0]*kv[0] + kv[1]*kv[1] + kv[2]*kv[2] + kv[3]*kv[3];
    const f32x4 dv = qv - kv;
    float ds = dv[0]*dv[0] + dv[1]*dv[1] + dv[2]*dv[2] + dv[3]*dv[3];

    bf16x4 qo, ko;
    #pragma unroll
    for (int i = 0; i < 4; ++i) { qo[i] = (bf16_t)qv[i]; ko[i] = (bf16_t)kv[i]; }

    const int G = p >> 5, l31 = p & 31;
    const int kk = lane >> 2, h = (lane >> 1) & 1, j0 = (lane & 1) * 4;
    const size_t base = (size_t)G * GS;
    const size_t off  = base + (size_t)(kk * 64 + h * 32 + l31) * 8 + j0;
    *(bf16x4*)(qb2 + off) = qo;
    *(bf16x4*)(kb2 + off) = ko;

    #pragma unroll
    for (int s = 32; s > 0; s >>= 1) {
        qs += __shfl_xor(qs, s);
        ks += __shfl_xor(ks, s);
        ds += __shfl_xor(ds, s);
    }

    // Pad frag kk=16 (dims 256..271). q' = [qhi,qlo,1,1,0..], k' = [1,1,khi,klo,0..]
    // so extra-dim dot = -(qs+ks)/2 with bf16 hi/lo split (norm error < 0.01).
    if (lane < 4) {
        const int hh = lane & 1;           // h of the pad block this lane writes
        bf16x8 v;
        #pragma unroll
        for (int i = 0; i < 8; ++i) v[i] = (bf16_t)0.0f;
        if (lane == 0) {                   // q', dims 256..263
            const float qh = -0.5f * qs;
            const bf16_t q1 = (bf16_t)qh;
            v[0] = q1; v[1] = (bf16_t)(qh - (float)q1);
            v[2] = (bf16_t)1.0f; v[3] = (bf16_t)1.0f;
        } else if (lane == 2) {            // k', dims 256..263
            const float kh = -0.5f * ks;
            const bf16_t k1 = (bf16_t)kh;
            v[0] = (bf16_t)1.0f; v[1] = (bf16_t)1.0f;
            v[2] = k1; v[3] = (bf16_t)(kh - (float)k1);
        }
        bf16_t* dstp = (lane < 2) ? qb2 : kb2;
        *(bf16x8*)(dstp + base + (size_t)(1024 + hh * 32 + l31) * 8) = v;
    }
    if (lane == 0)
        diag2[p] = (float)(-C2) * __builtin_amdgcn_sqrtf(ds);  // exact diag, log2
}

// ---------------------------------------------------------------------------
// Stage one 32-col B tile (17408 B, frag-major) into LDS via global_load_lds
// width-16. LDS dst = wave-uniform base (+ implicit lane*16).
// Waves 0-3 load 4x1KB each; wave 0 loads the 17th-fragment KB extra (5 loads).
// Safety model (round 7): every phase ends with s_waitcnt vmcnt(0)+barrier,
// so a tile staged at phase-T top is globally visible entering phase T+1.
// The stage still has the whole compute phase (~1500 cyc >> L2 latency) in
// flight — overlap preserved, and the cross-wave visibility race of the
// counted-vmcnt variants (R3/R6) is closed.
// ---------------------------------------------------------------------------
__device__ __forceinline__ void stage(const bf16_t* __restrict__ kb2,
                                      int Gc, int wave, int lane, char* dst)
{
    __builtin_assume(wave >= 0 && wave < 4);
    __builtin_assume(lane >= 0 && lane < 64);
    const bf16_t* src = kb2 + (size_t)Gc * GS + wave * 512 + lane * 8;
    char* d = dst + wave * 1024;
    #pragma unroll
    for (int j = 0; j < 4; ++j)
        __builtin_amdgcn_global_load_lds((const as1_void*)(src + j * 2048),
                                         (as3_void*)(d + j * 4096), 16, 0, 0);
    if (wave == 0)   // last 1 KB (17th fragment block)
        __builtin_amdgcn_global_load_lds((const as1_void*)(src + 4 * 2048),
                                         (as3_void*)(d + 4 * 4096), 16, 0, 0);
}

// ---------------------------------------------------------------------------
// ROUND-7 CORE CHANGE.  R6 counters decompose as sum-of-pipes with ZERO
// overlap: MFMA 14.6us (MfmaUtil 27.5%) + VALU ~13us (VALUBusy 24.6%) +
// TRANS(sqrt) ~13.6us + LDS ~11us ~= 52us wall.  At ~280 regs/wave only 1
// wave/SIMD is resident, and program order [MFMA cluster][epilogue] serializes
// the pipes.  Fix (uses the 232 free regs at 1 wave/SIMD):
//  (a) 4 independent MFMA chains (even/odd kk x 2 groups) — same-chain
//      separation 4 MFMAs = 128cy, covering dependent-MFMA latency (m119's
//      peak probe needed >=2 independent chains).
//  (b) Ping-pong deferred epilogue: phase T's MFMAs (set P) issue while set
//      Q's sqrt/exp2 epilogue (phase T-1 output) fills the MFMA shadow —
//      register-only ops, freely schedulable by the compiler within the BB.
// PH_MFMA: ds_read tile T + 34 MFMAs into the named 4-chain set (C=ZZ on the
// first kk pair re-zeroes the set — no v_mov zero-init per phase).
// EPI: chain-combine + sqrt + fast-exp2-bitcast + accumulate into l0/l1.
// ---------------------------------------------------------------------------
#define PH_MFMA(T, Pe0, Po0, Pe1, Po1)                                         \
  do {                                                                         \
    const bf16_t* bp = (const bf16_t*)smem[(T) & 1] + lane * 8;                \
    bf16x8 be = *(const bf16x8*)(bp);                                          \
    bf16x8 bo = *(const bf16x8*)(bp + 512);                                    \
    __builtin_amdgcn_s_setprio(1);                                             \
    Pe0 = __builtin_amdgcn_mfma_f32_32x32x16_bf16(a0[0], be, ZZ, 0, 0, 0);     \
    Pe1 = __builtin_amdgcn_mfma_f32_32x32x16_bf16(a1[0], be, ZZ, 0, 0, 0);     \
    Po0 = __builtin_amdgcn_mfma_f32_32x32x16_bf16(a0[1], bo, ZZ, 0, 0, 0);     \
    Po1 = __builtin_amdgcn_mfma_f32_32x32x16_bf16(a1[1], bo, ZZ, 0, 0, 0);     \
    _Pragma("unroll")                                                          \
    for (int kk = 2; kk < NKF; kk += 2) {                                      \
        be = *(const bf16x8*)(bp + kk * 512);                                  \
        Pe0 = __builtin_amdgcn_mfma_f32_32x32x16_bf16(a0[kk], be, Pe0,0,0,0);  \
        Pe1 = __builtin_amdgcn_mfma_f32_32x32x16_bf16(a1[kk], be, Pe1,0,0,0);  \
        if (kk + 1 < NKF) {                                                    \
            bo = *(const bf16x8*)(bp + (kk + 1) * 512);                        \
            Po0 = __builtin_amdgcn_mfma_f32_32x32x16_bf16(a0[kk+1], bo, Po0,0,0,0); \
            Po1 = __builtin_amdgcn_mfma_f32_32x32x16_bf16(a1[kk+1], bo, Po1,0,0,0); \
        }                                                                      \
    }                                                                          \
    __builtin_amdgcn_s_setprio(0);                                             \
  } while (0)

#define EPI(Pe0, Po0, Pe1, Po1)                                                \
  do {                                                                         \
    _Pragma("unroll")                                                          \
    for (int i = 0; i < 16; ++i) {                                             \
        const float s0 = Pe0[i] + Po0[i];                                      \
        const float t0 = __builtin_amdgcn_sqrtf(-s0);                          \
        const float u0 = fmaxf(fmaf(t0, COEF, KBIAS), 0.0f);                   \
        l0[i] += __uint_as_float((unsigned)u0);                                \
        const float s1 = Pe1[i] + Po1[i];                                      \
        const float t1 = __builtin_amdgcn_sqrtf(-s1);                          \
        const float u1 = fmaxf(fmaf(t1, COEF, KBIAS), 0.0f);                   \
        l1[i] += __uint_as_float((unsigned)u1);                                \
    }                                                                          \
  } while (0)

// drain own staging + LDS reads, then barrier: next phase may safely read the
// tile staged this phase and overwrite the buffer read this phase.
#define PH_BOT() \
    asm volatile("s_waitcnt vmcnt(0) lgkmcnt(0)\n\ts_barrier" ::: "memory")

// ---------------------------------------------------------------------------
// Kernel 2: fused (QK' GEMM -> -dist^2/2) + fixed-shift exp2 accumulation +
// cross-block merge via atomicAdd + last-block final loss reduction.
// Wave = 64 rows (2 groups) x 32 cols; block = 4 waves = 256 rows.
// launch_bounds(256,1): ~330 regs/wave (136 A + 128 acc pingpong + 32 l +
// temps) -> 1 wave/SIMD, NO spill (a (256,2) cap would force scratch, R2).
// Grid 32x16 XCD-swizzled; 2 sequential block-rounds per CU.
// ---------------------------------------------------------------------------
__global__ __launch_bounds__(256, 1) void nce_main(
    const bf16_t* __restrict__ qb2, const bf16_t* __restrict__ kb2,
    const float* __restrict__ diag2, float* __restrict__ part_l,
    unsigned* __restrict__ cnt, float* __restrict__ out)
{
    const int tid  = threadIdx.x, wave = tid >> 6, lane = tid & 63;
    const int l31  = lane & 31, h = lane >> 5;

    // bijective XCD swizzle: lin%8 = XCD (HW round-robin); XCD (xr,xc) owns
    // rb in [xr*8,xr*8+8) x cy in [xc*8,xc*8+8)  (xr=xcd&3, xc=xcd>>2)
    const int lin = blockIdx.x + (blockIdx.y << 5);   // gridDim.x = 32
    const int xcd = lin & 7, idx = lin >> 3;          // idx 0..63
    const int rb  = (xcd & 3) * 8 + (idx & 7);        // row-block 0..31
    const int cy  = (xcd >> 2) * 8 + (idx >> 3);      // chunk 0..15
    const int G0  = rb * 8 + wave * 2;                // wave's first 32-row group
    const int c0g = cy * TCOLS;                       // first col-group of chunk

    __shared__ __align__(16) char smem[NBUF][TILEB];
    __shared__ int s_last;
    __shared__ float red[4];

    // prologue: stage tile 0, then A-fragment loads (all drained together)
    stage(kb2, c0g, wave, lane, smem[0]);

    bf16x8 a0[NKF], a1[NKF];   // 2 x 17 x 4 = 136 regs
    {
        const bf16_t* ap0 = qb2 + (size_t)G0 * GS + lane * 8;
        const bf16_t* ap1 = ap0 + GS;
        #pragma unroll
        for (int kk = 0; kk < NKF; ++kk) {
            a0[kk] = *(const bf16x8*)(ap0 + kk * 512);
            a1[kk] = *(const bf16x8*)(ap1 + kk * 512);
        }
    }

    float l0[16], l1[16];
    #pragma unroll
    for (int i = 0; i < 16; ++i) { l0[i] = 0.0f; l1[i] = 0.0f; }

    const f32x16 ZZ = {0,0,0,0,0,0,0,0,0,0,0,0,0,0,0,0};
    f32x16 pe0, po0, pe1, po1;   // ping set P (even phases + phase 0)
    f32x16 qe0, qo0, qe1, qo1;   // pong set Q (odd phases)

    // tile0 + A in place for everyone
    PH_BOT();

    // phase 0 (P), no deferred epilogue yet
    stage(kb2, c0g + 1, wave, lane, smem[1]);
    PH_MFMA(0, pe0, po0, pe1, po1);
    PH_BOT();

    // phases 1..14, two per iteration (static ping-pong names — rule #20)
    #pragma unroll 1
    for (int tt = 1; tt <= 13; tt += 2) {
        stage(kb2, c0g + tt + 1, wave, lane, smem[(tt + 1) & 1]);
        PH_MFMA(tt, qe0, qo0, qe1, qo1);      // MFMA tile tt into Q
        EPI(pe0, po0, pe1, po1);              // epilogue of tile tt-1 (P)
        PH_BOT();
        stage(kb2, c0g + tt + 2, wave, lane, smem[tt & 1]);
        PH_MFMA(tt + 1, pe0, po0, pe1, po1);  // MFMA tile tt+1 into P
        EPI(qe0, qo0, qe1, qo1);              // epilogue of tile tt (Q)
        PH_BOT();
    }
    // phase 15 (Q), no stage
    PH_MFMA(15, qe0, qo0, qe1, qo1);
    EPI(pe0, po0, pe1, po1);                  // epilogue of tile 14
    EPI(qe0, qo0, qe1, qo1);                  // epilogue of tile 15

    // sum l across the 32 column-lanes (plain adds — fixed shift, no max merge)
    #pragma unroll
    for (int s = 1; s < 32; s <<= 1) {
        #pragma unroll
        for (int i = 0; i < 16; ++i) {
            l0[i] += __shfl_xor(l0[i], s);
            l1[i] += __shfl_xor(l1[i], s);
        }
    }

    if (l31 == 0) {
        #pragma unroll
        for (int i = 0; i < 16; ++i) {
            const int r = (i & 3) + 8 * (i >> 2) + 4 * h;
            atomicAdd(&part_l[G0 * 32 + r], l0[i]);
            atomicAdd(&part_l[(G0 + 1) * 32 + r], l1[i]);
        }
    }

    __syncthreads();
    if (tid == 0) {
        __threadfence();
        s_last = (atomicAdd(&cnt[rb], 1u) == NCHUNK - 1) ? 1 : 0;
    }
    __syncthreads();
    if (s_last) {
        // all 16 chunk-blocks of this row-block done: finalize 256 rows
        const int row = rb * ROWBLK + tid;
        const float lf = atomicAdd(&part_l[row], 0.0f);   // coherent read
        float v = MEXP + __builtin_amdgcn_logf(lf) - diag2[row];  // log2 domain
        #pragma unroll
        for (int s = 1; s < 64; s <<= 1) v += __shfl_xor(v, s);
        if (lane == 0) red[wave] = v;
        __syncthreads();
        if (tid == 0)
            atomicAdd(out, (red[0] + red[1] + red[2] + red[3]) * (LN2 / (float)PP));
    }
}

// ---------------------------------------------------------------------------
extern "C" void kernel_launch(void* const* d_in, const int* in_sizes, int n_in,
                              void* d_out, int out_size, void* d_ws, size_t ws_size,
                              hipStream_t stream)
{
    const float* f1  = (const float*)d_in[0];   // [20000,256] f32
    const float* f2  = (const float*)d_in[1];   // [8192,256] f32
    const int*   map = (const int*)d_in[2];     // [8192] int
    float* out = (float*)d_out;

    // workspace layout (~8.98 MB)
    char* ws = (char*)d_ws;
    bf16_t*   qb2    = (bf16_t*)ws;                           // 256*8704*2 B
    bf16_t*   kb2    = qb2 + (size_t)256 * GS;                // 256*8704*2 B
    float*    diag2  = (float*)(ws + 2ull * 256 * GS * sizeof(bf16_t));
    float*    part_l = diag2 + PP;
    unsigned* cnt    = (unsigned*)(part_l + PP);

    nce_prep<<<PP / 4, 256, 0, stream>>>(f1, f2, map, qb2, kb2, diag2,
                                         part_l, cnt, out);
    nce_main<<<dim3(NROWBLK, NCHUNK), 256, 0, stream>>>(qb2, kb2, diag2,
                                                        part_l, cnt, out);
}

// Round 8
// 127.835 us; speedup vs baseline: 1.0245x; 1.0245x over previous
//
#include <hip/hip_runtime.h>
#include <hip/hip_bf16.h>

// Problem: features_1 [1,20000,256] f32, features_2 [1,8192,256] f32, map21 [8192] int
#define PP      8192
#define DIM     256
#define DIMP    272              // 256 + 16 pad dims (norm embedding in 4 of them)
#define NKF     17               // K fragments of 16
#define GS      (32 * DIMP)      // 8704 bf16 elems per 32-row group
#define NCHUNK  16               // column chunks (grid.y); chunk = 512 cols
#define TCOLS   16               // 32-col tiles per chunk
#define ROWBLK  256              // rows per main block (4 waves x 2 row-groups)
#define NROWBLK (PP / ROWBLK)    // 32
#define TILEB   (32 * DIMP * 2)  // 17408 B per 32-col B tile
#define NBUF    2                // LDS double buffer

typedef __bf16 bf16_t;
using bf16x8 = __attribute__((ext_vector_type(8))) __bf16;
using bf16x4 = __attribute__((ext_vector_type(4))) __bf16;
using f32x4  = __attribute__((ext_vector_type(4))) float;
using f32x16 = __attribute__((ext_vector_type(16))) float;

typedef __attribute__((address_space(1))) void as1_void;
typedef __attribute__((address_space(3))) void as3_void;

#define C2    20.609929155556618          // 1/(T*ln2): -dist -> log2-domain logit
#define MEXP  (-340.0f)                   // fixed log2 shift (safe: see analysis)
#define COEF  ((float)(-(C2 * 1.4142135623730951) * 8388608.0))  // -C2*sqrt(2)*2^23
#define KBIAS ((float)((127.0 + 340.0) * 8388608.0))             // (127 - MEXP)*2^23
#define LN2   0.6931471805599453f

// ---------------------------------------------------------------------------
// Kernel 1: gather + bf16 convert into frag-major layout + norm-embedding pad
// dims + exact fp32 diagonal logit. Also zero-inits part_l / counters / out.
// One wave per row p; lane covers k = lane*4 .. +3.   (UNCHANGED)
// ---------------------------------------------------------------------------
__global__ __launch_bounds__(256) void nce_prep(
    const float* __restrict__ f1, const float* __restrict__ f2,
    const int* __restrict__ map,
    bf16_t* __restrict__ qb2, bf16_t* __restrict__ kb2,
    float* __restrict__ diag2, float* __restrict__ part_l,
    unsigned* __restrict__ cnt, float* __restrict__ out)
{
    const int tid  = threadIdx.x;
    const int wave = tid >> 6, lane = tid & 63;
    const int p    = blockIdx.x * 4 + wave;
    const int gtid = blockIdx.x * 256 + tid;

    if (gtid < PP) part_l[gtid] = 0.0f;
    if (gtid < NROWBLK) cnt[gtid] = 0u;
    if (gtid == 0) out[0] = 0.0f;

    const int idx = map[p];
    const f32x4 qv = *(const f32x4*)(f1 + (size_t)idx * DIM + lane * 4);
    const f32x4 kv = *(const f32x4*)(f2 + (size_t)p * DIM + lane * 4);

    float qs = qv[0]*qv[0] + qv[1]*qv[1] + qv[2]*qv[2] + qv[3]*qv[3];
    float ks = kv[0]*kv[0] + kv[1]*kv[1] + kv[2]*kv[2] + kv[3]*kv[3];
    const f32x4 dv = qv - kv;
    float ds = dv[0]*dv[0] + dv[1]*dv[1] + dv[2]*dv[2] + dv[3]*dv[3];

    bf16x4 qo, ko;
    #pragma unroll
    for (int i = 0; i < 4; ++i) { qo[i] = (bf16_t)qv[i]; ko[i] = (bf16_t)kv[i]; }

    const int G = p >> 5, l31 = p & 31;
    const int kk = lane >> 2, h = (lane >> 1) & 1, j0 = (lane & 1) * 4;
    const size_t base = (size_t)G * GS;
    const size_t off  = base + (size_t)(kk * 64 + h * 32 + l31) * 8 + j0;
    *(bf16x4*)(qb2 + off) = qo;
    *(bf16x4*)(kb2 + off) = ko;

    #pragma unroll
    for (int s = 32; s > 0; s >>= 1) {
        qs += __shfl_xor(qs, s);
        ks += __shfl_xor(ks, s);
        ds += __shfl_xor(ds, s);
    }

    // Pad frag kk=16 (dims 256..271). q' = [qhi,qlo,1,1,0..], k' = [1,1,khi,klo,0..]
    // so extra-dim dot = -(qs+ks)/2 with bf16 hi/lo split (norm error < 0.01).
    if (lane < 4) {
        const int hh = lane & 1;           // h of the pad block this lane writes
        bf16x8 v;
        #pragma unroll
        for (int i = 0; i < 8; ++i) v[i] = (bf16_t)0.0f;
        if (lane == 0) {                   // q', dims 256..263
            const float qh = -0.5f * qs;
            const bf16_t q1 = (bf16_t)qh;
            v[0] = q1; v[1] = (bf16_t)(qh - (float)q1);
            v[2] = (bf16_t)1.0f; v[3] = (bf16_t)1.0f;
        } else if (lane == 2) {            // k', dims 256..263
            const float kh = -0.5f * ks;
            const bf16_t k1 = (bf16_t)kh;
            v[0] = (bf16_t)1.0f; v[1] = (bf16_t)1.0f;
            v[2] = k1; v[3] = (bf16_t)(kh - (float)k1);
        }
        bf16_t* dstp = (lane < 2) ? qb2 : kb2;
        *(bf16x8*)(dstp + base + (size_t)(1024 + hh * 32 + l31) * 8) = v;
    }
    if (lane == 0)
        diag2[p] = (float)(-C2) * __builtin_amdgcn_sqrtf(ds);  // exact diag, log2
}

// ---------------------------------------------------------------------------
// Stage one 32-col B tile (17408 B, frag-major) into LDS via global_load_lds
// width-16. LDS dst = wave-uniform base (+ implicit lane*16).
// Waves 0-3 load 4x1KB each; wave 0 loads the 17th-fragment KB extra (5 loads).
// Safety: every phase ends with vmcnt(0)+lgkmcnt(0)+barrier, so a tile staged
// at phase-T top is globally visible entering phase T+1; the stage has the
// whole compute phase (~1500+ cyc) in flight.
// ---------------------------------------------------------------------------
__device__ __forceinline__ void stage(const bf16_t* __restrict__ kb2,
                                      int Gc, int wave, int lane, char* dst)
{
    __builtin_assume(wave >= 0 && wave < 4);
    __builtin_assume(lane >= 0 && lane < 64);
    const bf16_t* src = kb2 + (size_t)Gc * GS + wave * 512 + lane * 8;
    char* d = dst + wave * 1024;
    #pragma unroll
    for (int j = 0; j < 4; ++j)
        __builtin_amdgcn_global_load_lds((const as1_void*)(src + j * 2048),
                                         (as3_void*)(d + j * 4096), 16, 0, 0);
    if (wave == 0)   // last 1 KB (17th fragment block)
        __builtin_amdgcn_global_load_lds((const as1_void*)(src + 4 * 2048),
                                         (as3_void*)(d + 4 * 4096), 16, 0, 0);
}

// ---------------------------------------------------------------------------
// ROUND-8.  Machine model calibrated from R6/R7 counters:
//   per-SIMD matrix busy = 34 MFMA x 32cy = 1088/phase; R6 phase wall 3970cy
//   fits dependent-MFMA latency ~128cy (2 chains @ spacing-2 -> 2x dilation)
//   + serial EPI; R7's setprio walls + unhoisted B-loads made it 5050.
// Fix set (all three together):
//   (a) 4 independent acc chains (CE0,CO0,CE1,CO1), issue spacing 4 = 128cy
//       -> back-to-back MFMA issue.
//   (b) NO setprio anywhere (it is a scheduling wall; R7 post-mortem).
//   (c) B-loads in double-quad windows issued 4-8 MFMAs ahead; EPI of the
//       PREVIOUS phase's acc set interleaved in source between MFMA quads —
//       register-only ops the scheduler can drop into MFMA shadows.
// Phase is one scheduling region between PH_BOT walls.
// ---------------------------------------------------------------------------
#define PH_BOT() \
    asm volatile("s_waitcnt vmcnt(0) lgkmcnt(0)\n\ts_barrier" ::: "memory")

#define LDB(dst, kkidx) dst = *(const bf16x8*)(bp + (kkidx) * 512)

#define MQZ(B0,B1,B2,B3, CE0,CO0,CE1,CO1)                                      \
    CE0 = __builtin_amdgcn_mfma_f32_32x32x16_bf16(a0[0], B0, ZZ, 0,0,0);       \
    CE1 = __builtin_amdgcn_mfma_f32_32x32x16_bf16(a1[0], B0, ZZ, 0,0,0);       \
    CO0 = __builtin_amdgcn_mfma_f32_32x32x16_bf16(a0[1], B1, ZZ, 0,0,0);       \
    CO1 = __builtin_amdgcn_mfma_f32_32x32x16_bf16(a1[1], B1, ZZ, 0,0,0);       \
    CE0 = __builtin_amdgcn_mfma_f32_32x32x16_bf16(a0[2], B2, CE0, 0,0,0);      \
    CE1 = __builtin_amdgcn_mfma_f32_32x32x16_bf16(a1[2], B2, CE1, 0,0,0);      \
    CO0 = __builtin_amdgcn_mfma_f32_32x32x16_bf16(a0[3], B3, CO0, 0,0,0);      \
    CO1 = __builtin_amdgcn_mfma_f32_32x32x16_bf16(a1[3], B3, CO1, 0,0,0);

#define MQ(K0, B0,B1,B2,B3, CE0,CO0,CE1,CO1)                                   \
    CE0 = __builtin_amdgcn_mfma_f32_32x32x16_bf16(a0[(K0)+0], B0, CE0, 0,0,0); \
    CE1 = __builtin_amdgcn_mfma_f32_32x32x16_bf16(a1[(K0)+0], B0, CE1, 0,0,0); \
    CO0 = __builtin_amdgcn_mfma_f32_32x32x16_bf16(a0[(K0)+1], B1, CO0, 0,0,0); \
    CO1 = __builtin_amdgcn_mfma_f32_32x32x16_bf16(a1[(K0)+1], B1, CO1, 0,0,0); \
    CE0 = __builtin_amdgcn_mfma_f32_32x32x16_bf16(a0[(K0)+2], B2, CE0, 0,0,0); \
    CE1 = __builtin_amdgcn_mfma_f32_32x32x16_bf16(a1[(K0)+2], B2, CE1, 0,0,0); \
    CO0 = __builtin_amdgcn_mfma_f32_32x32x16_bf16(a0[(K0)+3], B3, CO0, 0,0,0); \
    CO1 = __builtin_amdgcn_mfma_f32_32x32x16_bf16(a1[(K0)+3], B3, CO1, 0,0,0);

// EPI slice S (elements 4S..4S+3) of a 4-chain acc set into l0/l1.
// acc = -dist^2/2; 2^(lg-MEXP) via bitcast trick; negative -> clamp 0.
#define EPIS(S, E0,O0,E1,O1)                                                   \
    _Pragma("unroll")                                                          \
    for (int i = 4*(S); i < 4*(S)+4; ++i) {                                    \
        const float s0 = E0[i] + O0[i];                                        \
        const float t0 = __builtin_amdgcn_sqrtf(-s0);                          \
        const float u0 = fmaxf(fmaf(t0, COEF, KBIAS), 0.0f);                   \
        l0[i] += __uint_as_float((unsigned)u0);                                \
        const float s1 = E1[i] + O1[i];                                        \
        const float t1 = __builtin_amdgcn_sqrtf(-s1);                          \
        const float u1 = fmaxf(fmaf(t1, COEF, KBIAS), 0.0f);                   \
        l1[i] += __uint_as_float((unsigned)u1);                                \
    }

// One phase: MFMA tile T into set C*, EPI previous phase's set P* interleaved.
#define PHASE(T, CE0,CO0,CE1,CO1, PE0,PO0,PE1,PO1, DO_EPI, DOPRE)              \
  do {                                                                         \
    if (DOPRE) stage(kb2, c0g + (T) + 1, wave, lane, smem[((T) + 1) & 1]);     \
    const bf16_t* bp = (const bf16_t*)smem[(T) & 1] + lane * 8;                \
    bf16x8 bA0, bA1, bA2, bA3, bB0, bB1, bB2, bB3;                             \
    LDB(bA0, 0); LDB(bA1, 1); LDB(bA2, 2); LDB(bA3, 3);                        \
    LDB(bB0, 4); LDB(bB1, 5); LDB(bB2, 6); LDB(bB3, 7);                        \
    MQZ(bA0,bA1,bA2,bA3, CE0,CO0,CE1,CO1);                                     \
    if (DO_EPI) { EPIS(0, PE0,PO0,PE1,PO1); }                                  \
    LDB(bA0, 8); LDB(bA1, 9); LDB(bA2, 10); LDB(bA3, 11);                      \
    MQ(4, bB0,bB1,bB2,bB3, CE0,CO0,CE1,CO1);                                   \
    if (DO_EPI) { EPIS(1, PE0,PO0,PE1,PO1); }                                  \
    LDB(bB0, 12); LDB(bB1, 13); LDB(bB2, 14); LDB(bB3, 15);                    \
    MQ(8, bA0,bA1,bA2,bA3, CE0,CO0,CE1,CO1);                                   \
    if (DO_EPI) { EPIS(2, PE0,PO0,PE1,PO1); }                                  \
    LDB(bA0, 16);                                                              \
    MQ(12, bB0,bB1,bB2,bB3, CE0,CO0,CE1,CO1);                                  \
    if (DO_EPI) { EPIS(3, PE0,PO0,PE1,PO1); }                                  \
    CE0 = __builtin_amdgcn_mfma_f32_32x32x16_bf16(a0[16], bA0, CE0, 0,0,0);    \
    CE1 = __builtin_amdgcn_mfma_f32_32x32x16_bf16(a1[16], bA0, CE1, 0,0,0);    \
    PH_BOT();                                                                  \
  } while (0)

// ---------------------------------------------------------------------------
// Kernel 2: fused (QK' GEMM -> -dist^2/2) + fixed-shift exp2 accumulation +
// cross-block merge via atomicAdd + last-block final loss reduction.
// Wave = 64 rows (2 groups) x 32 cols; block = 4 waves = 256 rows.
// launch_bounds(256,1): ~360 total regs/wave (A 136 + acc P/Q 128 + l 32 +
// B-window 32 + misc) -> 1 wave/SIMD, no spill.  Grid 32x16 XCD-swizzled.
// ---------------------------------------------------------------------------
__global__ __launch_bounds__(256, 1) void nce_main(
    const bf16_t* __restrict__ qb2, const bf16_t* __restrict__ kb2,
    const float* __restrict__ diag2, float* __restrict__ part_l,
    unsigned* __restrict__ cnt, float* __restrict__ out)
{
    const int tid  = threadIdx.x, wave = tid >> 6, lane = tid & 63;
    const int l31  = lane & 31, h = lane >> 5;

    // bijective XCD swizzle: lin%8 = XCD (HW round-robin); XCD (xr,xc) owns
    // rb in [xr*8,xr*8+8) x cy in [xc*8,xc*8+8)  (xr=xcd&3, xc=xcd>>2)
    const int lin = blockIdx.x + (blockIdx.y << 5);   // gridDim.x = 32
    const int xcd = lin & 7, idx = lin >> 3;          // idx 0..63
    const int rb  = (xcd & 3) * 8 + (idx & 7);        // row-block 0..31
    const int cy  = (xcd >> 2) * 8 + (idx >> 3);      // chunk 0..15
    const int G0  = rb * 8 + wave * 2;                // wave's first 32-row group
    const int c0g = cy * TCOLS;                       // first col-group of chunk

    __shared__ __align__(16) char smem[NBUF][TILEB];
    __shared__ int s_last;
    __shared__ float red[4];

    // prologue: stage tile 0, then A-fragment loads (all drained together)
    stage(kb2, c0g, wave, lane, smem[0]);

    bf16x8 a0[NKF], a1[NKF];   // 2 x 17 x 4 = 136 regs
    {
        const bf16_t* ap0 = qb2 + (size_t)G0 * GS + lane * 8;
        const bf16_t* ap1 = ap0 + GS;
        #pragma unroll
        for (int kk = 0; kk < NKF; ++kk) {
            a0[kk] = *(const bf16x8*)(ap0 + kk * 512);
            a1[kk] = *(const bf16x8*)(ap1 + kk * 512);
        }
    }

    float l0[16], l1[16];
    #pragma unroll
    for (int i = 0; i < 16; ++i) { l0[i] = 0.0f; l1[i] = 0.0f; }

    const f32x16 ZZ = {0,0,0,0,0,0,0,0,0,0,0,0,0,0,0,0};
    f32x16 pe0, po0, pe1, po1;   // set P
    f32x16 qe0, qo0, qe1, qo1;   // set Q

    PH_BOT();   // tile0 + A in place for everyone

    // phase 0 -> P (no deferred EPI yet)
    PHASE(0, pe0,po0,pe1,po1, qe0,qo0,qe1,qo1, false, true);

    // phases 1..14, two per iteration (static ping-pong names — rule #20)
    #pragma unroll 1
    for (int tt = 1; tt <= 13; tt += 2) {
        PHASE(tt,     qe0,qo0,qe1,qo1, pe0,po0,pe1,po1, true, true);
        PHASE(tt + 1, pe0,po0,pe1,po1, qe0,qo0,qe1,qo1, true, true);
    }
    // phase 15 -> Q (no stage), EPI of tile 14 (P) interleaved
    PHASE(15, qe0,qo0,qe1,qo1, pe0,po0,pe1,po1, true, false);
    // final EPI of tile 15 (Q)
    EPIS(0, qe0,qo0,qe1,qo1);
    EPIS(1, qe0,qo0,qe1,qo1);
    EPIS(2, qe0,qo0,qe1,qo1);
    EPIS(3, qe0,qo0,qe1,qo1);

    // sum l across the 32 column-lanes (plain adds — fixed shift, no max merge)
    #pragma unroll
    for (int s = 1; s < 32; s <<= 1) {
        #pragma unroll
        for (int i = 0; i < 16; ++i) {
            l0[i] += __shfl_xor(l0[i], s);
            l1[i] += __shfl_xor(l1[i], s);
        }
    }

    if (l31 == 0) {
        #pragma unroll
        for (int i = 0; i < 16; ++i) {
            const int r = (i & 3) + 8 * (i >> 2) + 4 * h;
            atomicAdd(&part_l[G0 * 32 + r], l0[i]);
            atomicAdd(&part_l[(G0 + 1) * 32 + r], l1[i]);
        }
    }

    __syncthreads();
    if (tid == 0) {
        __threadfence();
        s_last = (atomicAdd(&cnt[rb], 1u) == NCHUNK - 1) ? 1 : 0;
    }
    __syncthreads();
    if (s_last) {
        // all 16 chunk-blocks of this row-block done: finalize 256 rows
        const int row = rb * ROWBLK + tid;
        const float lf = atomicAdd(&part_l[row], 0.0f);   // coherent read
        float v = MEXP + __builtin_amdgcn_logf(lf) - diag2[row];  // log2 domain
        #pragma unroll
        for (int s = 1; s < 64; s <<= 1) v += __shfl_xor(v, s);
        if (lane == 0) red[wave] = v;
        __syncthreads();
        if (tid == 0)
            atomicAdd(out, (red[0] + red[1] + red[2] + red[3]) * (LN2 / (float)PP));
    }
}

// ---------------------------------------------------------------------------
extern "C" void kernel_launch(void* const* d_in, const int* in_sizes, int n_in,
                              void* d_out, int out_size, void* d_ws, size_t ws_size,
                              hipStream_t stream)
{
    const float* f1  = (const float*)d_in[0];   // [20000,256] f32
    const float* f2  = (const float*)d_in[1];   // [8192,256] f32
    const int*   map = (const int*)d_in[2];     // [8192] int
    float* out = (float*)d_out;

    // workspace layout (~8.98 MB)
    char* ws = (char*)d_ws;
    bf16_t*   qb2    = (bf16_t*)ws;                           // 256*8704*2 B
    bf16_t*   kb2    = qb2 + (size_t)256 * GS;                // 256*8704*2 B
    float*    diag2  = (float*)(ws + 2ull * 256 * GS * sizeof(bf16_t));
    float*    part_l = diag2 + PP;
    unsigned* cnt    = (unsigned*)(part_l + PP);

    nce_prep<<<PP / 4, 256, 0, stream>>>(f1, f2, map, qb2, kb2, diag2,
                                         part_l, cnt, out);
    nce_main<<<dim3(NROWBLK, NCHUNK), 256, 0, stream>>>(qb2, kb2, diag2,
                                                        part_l, cnt, out);
}